// Round 2
// baseline (2892.566 us; speedup 1.0000x reference)
//
#include <hip/hip_runtime.h>

// Jamba sparse MoE: T=32768 tokens, D=1024, F=2048, E=16, top-2.
// Pipeline: transpose/cast weights -> router (fused x->bf16, LDS-aggregated
// counts) -> scan -> perm (ballot-ranked, block-aggregated cursors) ->
// grouped gate/up GEMM (fused SiLU*up) -> grouped down GEMM with weighted
// atomic scatter into out.
//
// R1 lesson: 131072 device atomics into ONE cacheline cost 768us. Counters/
// cursors padded to 1 line each and aggregated per-block in LDS first.
// R2: gateup/down moved from the m97 2-barrier structure (MfmaUtil 34%,
// 5.6e7 LDS bank-conflict cycles) to the 8-phase-family schedule:
//  - 256-row tiles (derived from the 128-row tile list by skipping odd
//    local tiles), 512 threads / 8 waves, per-wave 64x64 output.
//  - 4-slot LDS ring, depth-3 global_load_lds prefetch, counted
//    s_waitcnt vmcnt(8/6) at tile boundaries (never 0 mid-loop), raw
//    s_barrier (NOT __syncthreads -> no full vmcnt drain).
//  - XOR swizzle (16B-slot ^= (row>>1)&3) applied on the per-lane GLOBAL
//    source addr (gload_lds writes linearly) and on the ds_read addr:
//    fragment reads go ~8-way -> 2-way (free).
//  - lgkmcnt(0)+sched_barrier(0) then setprio(1) around 16-MFMA clusters.
// R3: resubmit of R2 unchanged — R2 bench failed on GPUAcquisitionTimeout
// (broker at capacity), kernel never executed. Audit of vmcnt accounting,
// ring hazards, swizzle involution, odd-tile skip found no defect.

#define T_ 32768
#define D_ 1024
#define F_ 2048
#define E_ 16
#define P_ 65536      // T_ * TOP_K
#define MAXTILES 528  // sum ceil(n_e/128) <= P/128 + E - 1

typedef __bf16 bf16x8 __attribute__((ext_vector_type(8)));
typedef float floatx4 __attribute__((ext_vector_type(4)));
typedef unsigned short bfu;  // raw bf16 bits storage

// ws layout (bytes)
#define O_XB 0ull                       // x bf16            [T, D]    64 MB
#define O_WG 67108864ull                // gate^T bf16       [E][F][D] 64 MB
#define O_WU 134217728ull               // up^T bf16         [E][F][D] 64 MB
#define O_WD 201326592ull               // down^T bf16       [E][D][F] 64 MB
#define O_H  268435456ull               // h bf16            [P, F]   256 MB
#define O_CW 536870912ull               // combine weight    [P] f32
#define O_EI 537133056ull               // expert idx        [P] i32
#define O_PM 537395200ull               // perm pos->pairid  [P] i32
#define O_MT 537657344ull               // meta ints
// meta int layout (cacheline-padded hot counters):
//   counts:  meta[e*32]            e<16   (one 128B line per counter)
//   cursors: meta[512 + e*32]      e<16
//   offsets: meta[1024 + e]        e<17   (exclusive scan, [16]=total)
//   ntiles:  meta[1041]
//   tile_e:  meta[1056 + i]        i<528
//   tile_r:  meta[1600 + i]        i<528

__device__ __forceinline__ unsigned short f2bf(float f) {
  unsigned int u = __float_as_uint(f);
  u = u + 0x7fffu + ((u >> 16) & 1u);  // RNE
  return (unsigned short)(u >> 16);
}

__device__ __forceinline__ void gload16(const void* g, void* l) {
  __builtin_amdgcn_global_load_lds(
      (const __attribute__((address_space(1))) unsigned int*)g,
      (__attribute__((address_space(3))) unsigned int*)l, 16, 0, 0);
}

// src [E][R][C] fp32 -> dst [E][C][R] bf16
__global__ __launch_bounds__(256) void transpose_cast_kernel(
    const float* __restrict__ src, bfu* __restrict__ dst, int R, int C) {
  __shared__ float tile[64][65];
  const int e = blockIdx.z;
  const int r0 = blockIdx.y * 64, c0 = blockIdx.x * 64;
  const size_t base = (size_t)e * R * C;
  const int tid = threadIdx.x;
  const int rr = tid >> 4;
  const int cc = (tid & 15) * 4;
  const float* sp = src + base + (size_t)(r0 + rr) * C + (c0 + cc);
#pragma unroll
  for (int i = 0; i < 4; ++i) {
    float4 v = *(const float4*)(sp + (size_t)(i * 16) * C);
    tile[rr + i * 16][cc + 0] = v.x;
    tile[rr + i * 16][cc + 1] = v.y;
    tile[rr + i * 16][cc + 2] = v.z;
    tile[rr + i * 16][cc + 3] = v.w;
  }
  __syncthreads();
  const int oc = tid >> 2;
  const int sg = (tid & 3) * 16;
  union { bfu b[16]; uint4 q[2]; } u;
#pragma unroll
  for (int j = 0; j < 16; ++j) u.b[j] = f2bf(tile[sg + j][oc]);
  bfu* dp = dst + base + (size_t)(c0 + oc) * R + (r0 + sg);
  ((uint4*)dp)[0] = u.q[0];
  ((uint4*)dp)[1] = u.q[1];
}

// 256 threads = 4 waves; each wave handles 8 tokens; block = 32 tokens.
__global__ __launch_bounds__(256) void router_kernel(
    const float* __restrict__ x, const float* __restrict__ rw,
    bfu* __restrict__ xb, float* __restrict__ logits,
    float* __restrict__ cw, int* __restrict__ eidx, int* __restrict__ meta) {
  __shared__ int hist[16];
  const int tid = threadIdx.x, lane = tid & 63, wave = tid >> 6;
  if (tid < 16) hist[tid] = 0;
  __syncthreads();

  for (int tk = 0; tk < 8; ++tk) {
    const int t = blockIdx.x * 32 + wave * 8 + tk;
    const float* xp = x + (size_t)t * D_ + lane * 16;
    float xv[16];
#pragma unroll
    for (int i = 0; i < 4; ++i) {
      float4 v = ((const float4*)xp)[i];
      xv[i * 4 + 0] = v.x; xv[i * 4 + 1] = v.y;
      xv[i * 4 + 2] = v.z; xv[i * 4 + 3] = v.w;
    }
    union { bfu b[16]; uint4 q[2]; } u;
#pragma unroll
    for (int i = 0; i < 16; ++i) u.b[i] = f2bf(xv[i]);
    uint4* xbp = (uint4*)(xb + (size_t)t * D_ + lane * 16);
    xbp[0] = u.q[0];
    xbp[1] = u.q[1];

    float l[16];
#pragma unroll
    for (int e = 0; e < 16; ++e) {
      const float* wp = rw + (size_t)e * D_ + lane * 16;
      float s = 0.f;
#pragma unroll
      for (int i = 0; i < 4; ++i) {
        float4 w = ((const float4*)wp)[i];
        s += xv[i * 4 + 0] * w.x + xv[i * 4 + 1] * w.y +
             xv[i * 4 + 2] * w.z + xv[i * 4 + 3] * w.w;
      }
#pragma unroll
      for (int off = 32; off; off >>= 1) s += __shfl_xor(s, off);
      l[e] = s;
    }
    float m = l[0];
#pragma unroll
    for (int e = 1; e < 16; ++e) m = fmaxf(m, l[e]);
    float p[16], sum = 0.f;
#pragma unroll
    for (int e = 0; e < 16; ++e) { p[e] = expf(l[e] - m); sum += p[e]; }
    int e0 = 0; float b0 = p[0];
#pragma unroll
    for (int e = 1; e < 16; ++e) if (p[e] > b0) { b0 = p[e]; e0 = e; }
    int e1 = -1; float b1 = -1.f;
#pragma unroll
    for (int e = 0; e < 16; ++e) if (e != e0 && p[e] > b1) { b1 = p[e]; e1 = e; }
    if (lane < 16) logits[(size_t)t * 16 + lane] = l[lane];
    if (lane == 0) {
      float inv = 1.f / sum;
      cw[t * 2 + 0] = b0 * inv;
      cw[t * 2 + 1] = b1 * inv;
      eidx[t * 2 + 0] = e0;
      eidx[t * 2 + 1] = e1;
      atomicAdd(&hist[e0], 1);
      atomicAdd(&hist[e1], 1);
    }
  }
  __syncthreads();
  if (tid < 16) atomicAdd(&meta[tid * 32], hist[tid]);
}

__global__ void scan_kernel(int* __restrict__ meta) {
  if (threadIdx.x != 0) return;
  int off = 0, nt = 0;
  for (int e = 0; e < 16; ++e) {
    meta[1024 + e] = off;
    int n = meta[e * 32];
    for (int r = 0; r < n; r += 128) {
      meta[1056 + nt] = e;
      meta[1600 + nt] = off + r;
      ++nt;
    }
    off += n;
  }
  meta[1040] = off;
  meta[1041] = nt;
}

// ballot-ranked placement: one cursor atomic per (expert, block)
__global__ __launch_bounds__(256) void perm_kernel(
    const int* __restrict__ eidx, int* __restrict__ meta, int* __restrict__ perm) {
  __shared__ int wcnt[4][16];
  __shared__ int bbase[16];
  const int tid = threadIdx.x, lane = tid & 63, wave = tid >> 6;
  const int p = blockIdx.x * 256 + tid;
  const int e = eidx[p];
  const unsigned long long lt = (lane == 63) ? ~0ull >> 1
                                             : (1ull << lane) - 1;
  int rank = 0;
#pragma unroll
  for (int q = 0; q < 16; ++q) {
    unsigned long long m = __ballot(e == q);
    if (e == q) rank = __popcll(m & lt);
    if (lane == 0) wcnt[wave][q] = __popcll(m);
  }
  __syncthreads();
  if (tid < 16) {
    int s = 0;
#pragma unroll
    for (int w = 0; w < 4; ++w) { int c = wcnt[w][tid]; wcnt[w][tid] = s; s += c; }
    bbase[tid] = atomicAdd(&meta[512 + tid * 32], s);
  }
  __syncthreads();
  perm[meta[1024 + e] + bbase[e] + wcnt[wave][e] + rank] = p;
}

// -------- R2 grouped gate/up GEMM: 256x128 tile, BK=32, 8 waves ----------
// h[p, f] = silu(x@Wg) * (x@Wu). 4-slot LDS ring, depth-3 prefetch.
__global__ __launch_bounds__(512, 2) void gateup_kernel(
    const bfu* __restrict__ xb, const bfu* __restrict__ wg,
    const bfu* __restrict__ wu, bfu* __restrict__ h,
    const int* __restrict__ perm, const int* __restrict__ meta) {
  __shared__ bfu sA[4][8192];   // [slot][256 rows x 32 k] swizzled
  __shared__ bfu sG[4][4096];   // [slot][128 f    x 32 k] swizzled
  __shared__ bfu sU[4][4096];
  __shared__ int rowtok[256];

  const int tile = blockIdx.y;
  if (tile >= meta[1041]) return;
  const int e = meta[1056 + tile];
  const int row0 = meta[1600 + tile];
  if ((row0 - meta[1024 + e]) & 128) return;   // odd 128-tile: merged into even
  const int nvalid = meta[1025 + e] - row0;    // rows this 256-tile owns (<=256 used)
  const int n0 = blockIdx.x * 128;
  const int tid = threadIdx.x, lane = tid & 63, wave = tid >> 6;
  const int wm = wave >> 1, wn = wave & 1;

  if (tid < 256) {
    int r = tid < nvalid ? tid : (nvalid - 1);
    rowtok[tid] = perm[row0 + r] >> 1;
  }
  __syncthreads();

  // staging geometry: thread loads 16B; row = wave*16 + lane/4.
  // Global source k is pre-swizzled so the linear LDS write lands the
  // swizzled layout: 16B-slot s_phys holds logical slot s_phys^((row>>1)&3).
  const int srow = wave * 16 + (lane >> 2);                 // 0..127
  const int kx = ((lane & 3) ^ ((srow >> 1) & 3)) << 3;     // elems in [0,32)
  const bfu* aSrc0 = xb + (size_t)rowtok[srow] * D_ + kx;
  const bfu* aSrc1 = xb + (size_t)rowtok[srow + 128] * D_ + kx;
  const size_t wbase = (size_t)e * F_ * D_;
  const bfu* gSrc = wg + wbase + (size_t)(n0 + srow) * D_ + kx;
  const bfu* uSrc = wu + wbase + (size_t)(n0 + srow) * D_ + kx;
  const int dA0 = wave * 512;          // wave-uniform LDS dest (elems)
  const int dA1 = 4096 + wave * 512;
  const int dB  = wave * 512;

  // fragment read offsets (swizzled): elem = row*32 + (kg^((row>>1)&3))*8
  const int kg = lane >> 4;
  int offA[4], offB[4];
#pragma unroll
  for (int i = 0; i < 4; ++i) {
    const int row = wm * 64 + i * 16 + (lane & 15);
    offA[i] = row * 32 + ((kg ^ ((row >> 1) & 3)) << 3);
    const int col = wn * 64 + i * 16 + (lane & 15);
    offB[i] = col * 32 + ((kg ^ ((col >> 1) & 3)) << 3);
  }

  floatx4 accg[4][4] = {};
  floatx4 accu[4][4] = {};

  // prologue: stage K-tiles 0,1,2 (order per tile: A0,A1,G,U)
#pragma unroll
  for (int pt = 0; pt < 3; ++pt) {
    const int ko = pt * 32;
    gload16(aSrc0 + ko, &sA[pt][dA0]);
    gload16(aSrc1 + ko, &sA[pt][dA1]);
    gload16(gSrc + ko, &sG[pt][dB]);
    gload16(uSrc + ko, &sU[pt][dB]);
  }
  asm volatile("s_waitcnt vmcnt(8)" ::: "memory");  // tile 0 landed
  __builtin_amdgcn_s_barrier();

#pragma unroll 4
  for (int kt = 0; kt < 32; ++kt) {
    const int slot = kt & 3;
    bf16x8 af[4], bg[4], bu[4];
    // ---- phase 0: prefetch A(kt+3), read A+G frags, gate MFMAs ----
    if (kt < 29) {
      const int s2 = (kt + 3) & 3, ko = (kt + 3) * 32;
      gload16(aSrc0 + ko, &sA[s2][dA0]);
      gload16(aSrc1 + ko, &sA[s2][dA1]);
    }
#pragma unroll
    for (int i = 0; i < 4; ++i) af[i] = *(const bf16x8*)&sA[slot][offA[i]];
#pragma unroll
    for (int i = 0; i < 4; ++i) bg[i] = *(const bf16x8*)&sG[slot][offB[i]];
    __builtin_amdgcn_s_barrier();
    asm volatile("s_waitcnt lgkmcnt(0)" ::: "memory");
    __builtin_amdgcn_sched_barrier(0);
    __builtin_amdgcn_s_setprio(1);
#pragma unroll
    for (int mi = 0; mi < 4; ++mi)
#pragma unroll
      for (int ni = 0; ni < 4; ++ni)
        accg[mi][ni] = __builtin_amdgcn_mfma_f32_16x16x32_bf16(
            af[mi], bg[ni], accg[mi][ni], 0, 0, 0);
    __builtin_amdgcn_s_setprio(0);
    __builtin_amdgcn_s_barrier();
    // ---- phase 1: prefetch G,U(kt+3), read U frags, up MFMAs ----
    if (kt < 29) {
      const int s2 = (kt + 3) & 3, ko = (kt + 3) * 32;
      gload16(gSrc + ko, &sG[s2][dB]);
      gload16(uSrc + ko, &sU[s2][dB]);
    }
#pragma unroll
    for (int i = 0; i < 4; ++i) bu[i] = *(const bf16x8*)&sU[slot][offB[i]];
    __builtin_amdgcn_s_barrier();
    asm volatile("s_waitcnt lgkmcnt(0)" ::: "memory");
    __builtin_amdgcn_sched_barrier(0);
    __builtin_amdgcn_s_setprio(1);
#pragma unroll
    for (int mi = 0; mi < 4; ++mi)
#pragma unroll
      for (int ni = 0; ni < 4; ++ni)
        accu[mi][ni] = __builtin_amdgcn_mfma_f32_16x16x32_bf16(
            af[mi], bu[ni], accu[mi][ni], 0, 0, 0);
    __builtin_amdgcn_s_setprio(0);
    // tile boundary: next tile's 4 loads must be in LDS; keep rest in flight
    if (kt < 29)       asm volatile("s_waitcnt vmcnt(8)" ::: "memory");
    else if (kt == 29) asm volatile("s_waitcnt vmcnt(4)" ::: "memory");
    else if (kt == 30) asm volatile("s_waitcnt vmcnt(0)" ::: "memory");
    __builtin_amdgcn_s_barrier();
  }

  // epilogue: silu(g)*u -> bf16, repack 16x64 wave-private slabs (reuse sA)
  bfu* slab = &sA[0][0] + wave * 1024;
  const int sq = lane >> 4, sc = lane & 15;
  const int orow = lane >> 2, osg = (lane & 3) * 16;
#pragma unroll
  for (int mi = 0; mi < 4; ++mi) {
#pragma unroll
    for (int ni = 0; ni < 4; ++ni) {
      floatx4 g = accg[mi][ni], v = accu[mi][ni];
#pragma unroll
      for (int i = 0; i < 4; ++i) {
        float gv = g[i];
        float hv = (gv / (1.f + __expf(-gv))) * v[i];
        slab[(sq * 4 + i) * 64 + ni * 16 + sc] = f2bf(hv);
      }
    }
    const int prow = wm * 64 + mi * 16 + orow;
    if (prow < nvalid) {
      bfu* hp = h + (size_t)(row0 + prow) * F_ + (n0 + wn * 64 + osg);
      uint4 q0 = *(const uint4*)(slab + orow * 64 + osg);
      uint4 q1 = *(const uint4*)(slab + orow * 64 + osg + 8);
      ((uint4*)hp)[0] = q0;
      ((uint4*)hp)[1] = q1;
    }
  }
}

// -------- R2 grouped down GEMM: 256x128 tile, BK=32, 8 waves -------------
// out[tok, d] += w * (h @ Wd), atomic scatter. Same ring/swizzle schedule.
__global__ __launch_bounds__(512, 2) void down_kernel(
    const bfu* __restrict__ h, const bfu* __restrict__ wd,
    float* __restrict__ out, const float* __restrict__ cw,
    const int* __restrict__ perm, const int* __restrict__ meta) {
  __shared__ bfu sA[4][8192];   // [slot][256 rows x 32 k]
  __shared__ bfu sB[4][4096];   // [slot][128 d    x 32 k]
  __shared__ int rtok[256];
  __shared__ float rwt[256];

  const int tile = blockIdx.y;
  if (tile >= meta[1041]) return;
  const int e = meta[1056 + tile];
  const int row0 = meta[1600 + tile];
  if ((row0 - meta[1024 + e]) & 128) return;
  const int nvalid = meta[1025 + e] - row0;
  const int n0 = blockIdx.x * 128;
  const int tid = threadIdx.x, lane = tid & 63, wave = tid >> 6;
  const int wm = wave >> 1, wn = wave & 1;

  if (tid < 256) {
    if (tid < nvalid) {
      int pr = perm[row0 + tid];
      rtok[tid] = pr >> 1;
      rwt[tid] = cw[pr];
    } else {
      rtok[tid] = 0;
      rwt[tid] = 0.f;
    }
  }
  __syncthreads();

  const int srow = wave * 16 + (lane >> 2);
  const int kx = ((lane & 3) ^ ((srow >> 1) & 3)) << 3;
  const int ra = srow < nvalid ? srow : nvalid - 1;
  const int rb = (srow + 128) < nvalid ? (srow + 128) : nvalid - 1;
  const bfu* aSrc0 = h + (size_t)(row0 + ra) * F_ + kx;
  const bfu* aSrc1 = h + (size_t)(row0 + rb) * F_ + kx;
  const bfu* bSrc = wd + (size_t)e * D_ * F_ + (size_t)(n0 + srow) * F_ + kx;
  const int dA0 = wave * 512, dA1 = 4096 + wave * 512, dB = wave * 512;

  const int kg = lane >> 4;
  int offA[4], offB[4];
#pragma unroll
  for (int i = 0; i < 4; ++i) {
    const int row = wm * 64 + i * 16 + (lane & 15);
    offA[i] = row * 32 + ((kg ^ ((row >> 1) & 3)) << 3);
    const int col = wn * 64 + i * 16 + (lane & 15);
    offB[i] = col * 32 + ((kg ^ ((col >> 1) & 3)) << 3);
  }

  floatx4 acc[4][4] = {};

#pragma unroll
  for (int pt = 0; pt < 3; ++pt) {
    const int ko = pt * 32;
    gload16(aSrc0 + ko, &sA[pt][dA0]);
    gload16(aSrc1 + ko, &sA[pt][dA1]);
    gload16(bSrc + ko, &sB[pt][dB]);
  }
  asm volatile("s_waitcnt vmcnt(6)" ::: "memory");
  __builtin_amdgcn_s_barrier();

#pragma unroll 4
  for (int kt = 0; kt < 64; ++kt) {
    const int slot = kt & 3;
    if (kt < 61) {
      const int s2 = (kt + 3) & 3, ko = (kt + 3) * 32;
      gload16(aSrc0 + ko, &sA[s2][dA0]);
      gload16(aSrc1 + ko, &sA[s2][dA1]);
      gload16(bSrc + ko, &sB[s2][dB]);
    }
    bf16x8 af[4], bf_[4];
#pragma unroll
    for (int i = 0; i < 4; ++i) af[i] = *(const bf16x8*)&sA[slot][offA[i]];
#pragma unroll
    for (int i = 0; i < 4; ++i) bf_[i] = *(const bf16x8*)&sB[slot][offB[i]];
    __builtin_amdgcn_s_barrier();
    asm volatile("s_waitcnt lgkmcnt(0)" ::: "memory");
    __builtin_amdgcn_sched_barrier(0);
    __builtin_amdgcn_s_setprio(1);
#pragma unroll
    for (int mi = 0; mi < 4; ++mi)
#pragma unroll
      for (int ni = 0; ni < 4; ++ni)
        acc[mi][ni] = __builtin_amdgcn_mfma_f32_16x16x32_bf16(
            af[mi], bf_[ni], acc[mi][ni], 0, 0, 0);
    __builtin_amdgcn_s_setprio(0);
    if (kt < 61)       asm volatile("s_waitcnt vmcnt(6)" ::: "memory");
    else if (kt == 61) asm volatile("s_waitcnt vmcnt(3)" ::: "memory");
    else if (kt == 62) asm volatile("s_waitcnt vmcnt(0)" ::: "memory");
    __builtin_amdgcn_s_barrier();
  }

  const int sq = lane >> 4, sc = lane & 15;
#pragma unroll
  for (int mi = 0; mi < 4; ++mi) {
#pragma unroll
    for (int i = 0; i < 4; ++i) {
      const int r = wm * 64 + mi * 16 + sq * 4 + i;
      const float w = rwt[r];
      if (w != 0.f) {
        const int tok = rtok[r];
        float* op = out + (size_t)tok * D_ + n0 + wn * 64 + sc;
#pragma unroll
        for (int ni = 0; ni < 4; ++ni)
          atomicAdd(op + ni * 16, w * acc[mi][ni][i]);
      }
    }
  }
}

extern "C" void kernel_launch(void* const* d_in, const int* in_sizes, int n_in,
                              void* d_out, int out_size, void* d_ws, size_t ws_size,
                              hipStream_t stream) {
  const float* x  = (const float*)d_in[0];
  const float* rw = (const float*)d_in[1];
  const float* gw = (const float*)d_in[2];
  const float* uw = (const float*)d_in[3];
  const float* dw = (const float*)d_in[4];
  float* out = (float*)d_out;
  float* logits = out + (size_t)T_ * D_;

  char* ws = (char*)d_ws;
  bfu* xb  = (bfu*)(ws + O_XB);
  bfu* wgt = (bfu*)(ws + O_WG);
  bfu* wut = (bfu*)(ws + O_WU);
  bfu* wdt = (bfu*)(ws + O_WD);
  bfu* hb  = (bfu*)(ws + O_H);
  float* cwp = (float*)(ws + O_CW);
  int* eip  = (int*)(ws + O_EI);
  int* perm = (int*)(ws + O_PM);
  int* meta = (int*)(ws + O_MT);

  hipMemsetAsync(out, 0, (size_t)T_ * D_ * sizeof(float), stream);
  hipMemsetAsync(meta, 0, 4096, stream);

  transpose_cast_kernel<<<dim3(F_ / 64, D_ / 64, E_), 256, 0, stream>>>(gw, wgt, D_, F_);
  transpose_cast_kernel<<<dim3(F_ / 64, D_ / 64, E_), 256, 0, stream>>>(uw, wut, D_, F_);
  transpose_cast_kernel<<<dim3(D_ / 64, F_ / 64, E_), 256, 0, stream>>>(dw, wdt, F_, D_);

  router_kernel<<<T_ / 32, 256, 0, stream>>>(x, rw, xb, logits, cwp, eip, meta);
  scan_kernel<<<1, 64, 0, stream>>>(meta);
  perm_kernel<<<P_ / 256, 256, 0, stream>>>(eip, meta, perm);

  gateup_kernel<<<dim3(F_ / 128, MAXTILES), 512, 0, stream>>>(xb, wgt, wut, hb, perm, meta);
  down_kernel<<<dim3(D_ / 128, MAXTILES), 512, 0, stream>>>(hb, wdt, out, cwp, perm, meta);
}

// Round 4
// 1617.522 us; speedup vs baseline: 1.7883x; 1.7883x over previous
//
#include <hip/hip_runtime.h>

// Jamba sparse MoE: T=32768 tokens, D=1024, F=2048, E=16, top-2.
// Pipeline: transpose/cast weights -> router (fused x->bf16, LDS-aggregated
// counts) -> scan -> perm (ballot-ranked, block-aggregated cursors) ->
// grouped gate/up GEMM (fused SiLU*up) -> grouped down GEMM with weighted
// atomic scatter into out.
//
// R1 lesson: 131072 device atomics into ONE cacheline cost 768us -> padded
// counters + LDS aggregation.
// R2 lesson: 512-thr/1-block-per-CU lockstep ring schedule collapsed 2x
// (MfmaUtil 20/10%) — R0's perf came from 2 INDEPENDENT 256-thr blocks/CU
// overlapping each other's staging drains (m114). Swizzle machinery itself
// verified correct (down bank conflicts -> 0).
// R3: R0 sync structure (256 thr, single-buffer, __syncthreads drain,
// 2 blocks/CU) + BK=64 (halves drain events) + verified XOR swizzle
// (phys slot = logical ^ (row&7), pre-permuted global source, same
// involution on reads) + bijective XCD-chunked block remap for L2 locality.
// R4: resubmit of R3 unchanged — R3 bench failed on GPUAcquisitionTimeout
// (broker at capacity), kernel never executed. Re-audit of swizzle
// involution, fragment geometry, remap bijectivity, clamps found no defect.

#define T_ 32768
#define D_ 1024
#define F_ 2048
#define E_ 16
#define P_ 65536      // T_ * TOP_K
#define MAXTILES 528  // sum ceil(n_e/128) <= P/128 + E - 1

typedef __bf16 bf16x8 __attribute__((ext_vector_type(8)));
typedef float floatx4 __attribute__((ext_vector_type(4)));
typedef unsigned short bfu;  // raw bf16 bits storage

// ws layout (bytes)
#define O_XB 0ull                       // x bf16            [T, D]    64 MB
#define O_WG 67108864ull                // gate^T bf16       [E][F][D] 64 MB
#define O_WU 134217728ull               // up^T bf16         [E][F][D] 64 MB
#define O_WD 201326592ull               // down^T bf16       [E][D][F] 64 MB
#define O_H  268435456ull               // h bf16            [P, F]   256 MB
#define O_CW 536870912ull               // combine weight    [P] f32
#define O_EI 537133056ull               // expert idx        [P] i32
#define O_PM 537395200ull               // perm pos->pairid  [P] i32
#define O_MT 537657344ull               // meta ints
// meta int layout (cacheline-padded hot counters):
//   counts:  meta[e*32]            e<16   (one 128B line per counter)
//   cursors: meta[512 + e*32]      e<16
//   offsets: meta[1024 + e]        e<17   (exclusive scan, [16]=total)
//   ntiles:  meta[1041]
//   tile_e:  meta[1056 + i]        i<528
//   tile_r:  meta[1600 + i]        i<528

__device__ __forceinline__ unsigned short f2bf(float f) {
  unsigned int u = __float_as_uint(f);
  u = u + 0x7fffu + ((u >> 16) & 1u);  // RNE
  return (unsigned short)(u >> 16);
}

__device__ __forceinline__ void gload16(const void* g, void* l) {
  __builtin_amdgcn_global_load_lds(
      (const __attribute__((address_space(1))) unsigned int*)g,
      (__attribute__((address_space(3))) unsigned int*)l, 16, 0, 0);
}

// src [E][R][C] fp32 -> dst [E][C][R] bf16
__global__ __launch_bounds__(256) void transpose_cast_kernel(
    const float* __restrict__ src, bfu* __restrict__ dst, int R, int C) {
  __shared__ float tile[64][65];
  const int e = blockIdx.z;
  const int r0 = blockIdx.y * 64, c0 = blockIdx.x * 64;
  const size_t base = (size_t)e * R * C;
  const int tid = threadIdx.x;
  const int rr = tid >> 4;
  const int cc = (tid & 15) * 4;
  const float* sp = src + base + (size_t)(r0 + rr) * C + (c0 + cc);
#pragma unroll
  for (int i = 0; i < 4; ++i) {
    float4 v = *(const float4*)(sp + (size_t)(i * 16) * C);
    tile[rr + i * 16][cc + 0] = v.x;
    tile[rr + i * 16][cc + 1] = v.y;
    tile[rr + i * 16][cc + 2] = v.z;
    tile[rr + i * 16][cc + 3] = v.w;
  }
  __syncthreads();
  const int oc = tid >> 2;
  const int sg = (tid & 3) * 16;
  union { bfu b[16]; uint4 q[2]; } u;
#pragma unroll
  for (int j = 0; j < 16; ++j) u.b[j] = f2bf(tile[sg + j][oc]);
  bfu* dp = dst + base + (size_t)(c0 + oc) * R + (r0 + sg);
  ((uint4*)dp)[0] = u.q[0];
  ((uint4*)dp)[1] = u.q[1];
}

// 256 threads = 4 waves; each wave handles 8 tokens; block = 32 tokens.
__global__ __launch_bounds__(256) void router_kernel(
    const float* __restrict__ x, const float* __restrict__ rw,
    bfu* __restrict__ xb, float* __restrict__ logits,
    float* __restrict__ cw, int* __restrict__ eidx, int* __restrict__ meta) {
  __shared__ int hist[16];
  const int tid = threadIdx.x, lane = tid & 63, wave = tid >> 6;
  if (tid < 16) hist[tid] = 0;
  __syncthreads();

  for (int tk = 0; tk < 8; ++tk) {
    const int t = blockIdx.x * 32 + wave * 8 + tk;
    const float* xp = x + (size_t)t * D_ + lane * 16;
    float xv[16];
#pragma unroll
    for (int i = 0; i < 4; ++i) {
      float4 v = ((const float4*)xp)[i];
      xv[i * 4 + 0] = v.x; xv[i * 4 + 1] = v.y;
      xv[i * 4 + 2] = v.z; xv[i * 4 + 3] = v.w;
    }
    union { bfu b[16]; uint4 q[2]; } u;
#pragma unroll
    for (int i = 0; i < 16; ++i) u.b[i] = f2bf(xv[i]);
    uint4* xbp = (uint4*)(xb + (size_t)t * D_ + lane * 16);
    xbp[0] = u.q[0];
    xbp[1] = u.q[1];

    float l[16];
#pragma unroll
    for (int e = 0; e < 16; ++e) {
      const float* wp = rw + (size_t)e * D_ + lane * 16;
      float s = 0.f;
#pragma unroll
      for (int i = 0; i < 4; ++i) {
        float4 w = ((const float4*)wp)[i];
        s += xv[i * 4 + 0] * w.x + xv[i * 4 + 1] * w.y +
             xv[i * 4 + 2] * w.z + xv[i * 4 + 3] * w.w;
      }
#pragma unroll
      for (int off = 32; off; off >>= 1) s += __shfl_xor(s, off);
      l[e] = s;
    }
    float m = l[0];
#pragma unroll
    for (int e = 1; e < 16; ++e) m = fmaxf(m, l[e]);
    float p[16], sum = 0.f;
#pragma unroll
    for (int e = 0; e < 16; ++e) { p[e] = expf(l[e] - m); sum += p[e]; }
    int e0 = 0; float b0 = p[0];
#pragma unroll
    for (int e = 1; e < 16; ++e) if (p[e] > b0) { b0 = p[e]; e0 = e; }
    int e1 = -1; float b1 = -1.f;
#pragma unroll
    for (int e = 0; e < 16; ++e) if (e != e0 && p[e] > b1) { b1 = p[e]; e1 = e; }
    if (lane < 16) logits[(size_t)t * 16 + lane] = l[lane];
    if (lane == 0) {
      float inv = 1.f / sum;
      cw[t * 2 + 0] = b0 * inv;
      cw[t * 2 + 1] = b1 * inv;
      eidx[t * 2 + 0] = e0;
      eidx[t * 2 + 1] = e1;
      atomicAdd(&hist[e0], 1);
      atomicAdd(&hist[e1], 1);
    }
  }
  __syncthreads();
  if (tid < 16) atomicAdd(&meta[tid * 32], hist[tid]);
}

__global__ void scan_kernel(int* __restrict__ meta) {
  if (threadIdx.x != 0) return;
  int off = 0, nt = 0;
  for (int e = 0; e < 16; ++e) {
    meta[1024 + e] = off;
    int n = meta[e * 32];
    for (int r = 0; r < n; r += 128) {
      meta[1056 + nt] = e;
      meta[1600 + nt] = off + r;
      ++nt;
    }
    off += n;
  }
  meta[1040] = off;
  meta[1041] = nt;
}

// ballot-ranked placement: one cursor atomic per (expert, block)
__global__ __launch_bounds__(256) void perm_kernel(
    const int* __restrict__ eidx, int* __restrict__ meta, int* __restrict__ perm) {
  __shared__ int wcnt[4][16];
  __shared__ int bbase[16];
  const int tid = threadIdx.x, lane = tid & 63, wave = tid >> 6;
  const int p = blockIdx.x * 256 + tid;
  const int e = eidx[p];
  const unsigned long long lt = (lane == 63) ? ~0ull >> 1
                                             : (1ull << lane) - 1;
  int rank = 0;
#pragma unroll
  for (int q = 0; q < 16; ++q) {
    unsigned long long m = __ballot(e == q);
    if (e == q) rank = __popcll(m & lt);
    if (lane == 0) wcnt[wave][q] = __popcll(m);
  }
  __syncthreads();
  if (tid < 16) {
    int s = 0;
#pragma unroll
    for (int w = 0; w < 4; ++w) { int c = wcnt[w][tid]; wcnt[w][tid] = s; s += c; }
    bbase[tid] = atomicAdd(&meta[512 + tid * 32], s);
  }
  __syncthreads();
  perm[meta[1024 + e] + bbase[e] + wcnt[wave][e] + rank] = p;
}

// -------- R3 grouped gate/up GEMM: 128x128 tile, BK=64, 4 waves ----------
// h[p, f] = silu(x@Wg) * (x@Wu). R0 sync structure, swizzled LDS, XCD remap.
// LDS tile [128 rows][64 k] bf16; 16B phys slot p at row r holds logical
// k-slot p ^ (r&7) (source pre-permuted; gload_lds writes linearly).
__global__ __launch_bounds__(256, 2) void gateup_kernel(
    const bfu* __restrict__ xb, const bfu* __restrict__ wg,
    const bfu* __restrict__ wu, bfu* __restrict__ h,
    const int* __restrict__ perm, const int* __restrict__ meta) {
  __shared__ bfu As[128 * 64];
  __shared__ bfu Bg[128 * 64];
  __shared__ bfu Bu[128 * 64];
  __shared__ int rowtok[128];

  // XCD-chunked remap (bijective: NWG % 8 == 0): consecutive logical blocks
  // (sharing A-slab / same-expert B panels) stay on one XCD's L2.
  const int GX = F_ / 128;                   // 16
  const int NWG = GX * MAXTILES;             // 8448
  const int d = blockIdx.y * GX + blockIdx.x;
  const int wgi = (d & 7) * (NWG >> 3) + (d >> 3);
  const int tile = wgi / GX;
  const int n0 = (wgi % GX) * 128;

  if (tile >= meta[1041]) return;
  const int e = meta[1056 + tile];
  const int row0 = meta[1600 + tile];
  const int nvalid = meta[1025 + e] - row0;
  const int tid = threadIdx.x, lane = tid & 63, wave = tid >> 6;

  if (tid < 128) {
    int r = tid < nvalid ? tid : (nvalid - 1);
    rowtok[tid] = perm[row0 + r] >> 1;
  }
  __syncthreads();

  // staging: round j covers rows j*32 + wave*8 + (lane>>3); this thread's
  // phys 16B slot is (lane&7); global k-slot = (lane&7) ^ (row&7),
  // and row&7 == lane>>3 for every round (rounds step by 32).
  const int sr = wave * 8 + (lane >> 3);
  const int kx = ((lane & 7) ^ (lane >> 3)) << 3;   // elems
  const size_t wbase = (size_t)e * F_ * D_;
  const bfu* aP[4]; const bfu* gP[4]; const bfu* uP[4];
#pragma unroll
  for (int j = 0; j < 4; ++j) {
    const int row = j * 32 + sr;
    aP[j] = xb + (size_t)rowtok[row] * D_ + kx;
    gP[j] = wg + wbase + (size_t)(n0 + row) * D_ + kx;
    uP[j] = wu + wbase + (size_t)(n0 + row) * D_ + kx;
  }

  // fragment reads: row = wm + i*16 + (lane&15); logical slot kh*4+(lane>>4);
  // phys = logical ^ (row&7). kf XOR 32 flips slot bit2 (logical +4 = kh=1).
  const int wm = (wave >> 1) * 64, wn = (wave & 1) * 64;
  const int rb = lane & 15, kseg = lane >> 4, x7 = rb & 7;
  int offA[4], offB[4];
#pragma unroll
  for (int i = 0; i < 4; ++i) {
    offA[i] = (wm + i * 16 + rb) * 64 + ((kseg ^ x7) << 3);
    offB[i] = (wn + i * 16 + rb) * 64 + ((kseg ^ x7) << 3);
  }

  floatx4 accg[4][4] = {};
  floatx4 accu[4][4] = {};

  for (int k0 = 0; k0 < D_; k0 += 64) {
#pragma unroll
    for (int j = 0; j < 4; ++j) {
      const int db = (j * 32 + wave * 8) * 64;
      gload16(aP[j] + k0, As + db);
      gload16(gP[j] + k0, Bg + db);
      gload16(uP[j] + k0, Bu + db);
    }
    __syncthreads();
#pragma unroll
    for (int kh = 0; kh < 2; ++kh) {
      const int kf = kh << 5;  // elem-offset XOR 32 == logical slot ^4
      bf16x8 af[4], bg[4], bu[4];
#pragma unroll
      for (int i = 0; i < 4; ++i) {
        af[i] = *(const bf16x8*)&As[offA[i] ^ kf];
        bg[i] = *(const bf16x8*)&Bg[offB[i] ^ kf];
        bu[i] = *(const bf16x8*)&Bu[offB[i] ^ kf];
      }
#pragma unroll
      for (int mi = 0; mi < 4; ++mi)
#pragma unroll
        for (int ni = 0; ni < 4; ++ni) {
          accg[mi][ni] = __builtin_amdgcn_mfma_f32_16x16x32_bf16(
              af[mi], bg[ni], accg[mi][ni], 0, 0, 0);
          accu[mi][ni] = __builtin_amdgcn_mfma_f32_16x16x32_bf16(
              af[mi], bu[ni], accu[mi][ni], 0, 0, 0);
        }
    }
    __syncthreads();
  }

  // epilogue: silu(g)*u -> bf16, repack 16x64 slabs through LDS for 16B stores
  bfu* slab = As + wave * 1024;  // wave-private 16x64 bf16
  const int sq = lane >> 4, sc = lane & 15;
  const int orow = lane >> 2, osg = (lane & 3) * 16;
#pragma unroll
  for (int mi = 0; mi < 4; ++mi) {
    __syncthreads();
#pragma unroll
    for (int ni = 0; ni < 4; ++ni) {
      floatx4 g = accg[mi][ni], v = accu[mi][ni];
#pragma unroll
      for (int i = 0; i < 4; ++i) {
        float gv = g[i];
        float hv = (gv / (1.f + __expf(-gv))) * v[i];
        slab[(sq * 4 + i) * 64 + ni * 16 + sc] = f2bf(hv);
      }
    }
    __syncthreads();
    const int prow = wm + mi * 16 + orow;
    if (prow < nvalid) {
      bfu* hp = h + (size_t)(row0 + prow) * F_ + (n0 + wn + osg);
      uint4 q0 = *(const uint4*)(slab + orow * 64 + osg);
      uint4 q1 = *(const uint4*)(slab + orow * 64 + osg + 8);
      ((uint4*)hp)[0] = q0;
      ((uint4*)hp)[1] = q1;
    }
  }
}

// -------- R3 grouped down GEMM: 128x128 tile, BK=64, 4 waves -------------
// out[tok, d] += w * (h @ Wd), atomic scatter. Same structure as gateup.
__global__ __launch_bounds__(256, 2) void down_kernel(
    const bfu* __restrict__ h, const bfu* __restrict__ wd,
    float* __restrict__ out, const float* __restrict__ cw,
    const int* __restrict__ perm, const int* __restrict__ meta) {
  __shared__ bfu As[128 * 64];
  __shared__ bfu Bs[128 * 64];
  __shared__ int rtok[128];
  __shared__ float rwt[128];

  const int GX = D_ / 128;                   // 8
  const int NWG = GX * MAXTILES;             // 4224
  const int d = blockIdx.y * GX + blockIdx.x;
  const int wgi = (d & 7) * (NWG >> 3) + (d >> 3);
  const int tile = wgi / GX;
  const int n0 = (wgi % GX) * 128;

  if (tile >= meta[1041]) return;
  const int e = meta[1056 + tile];
  const int row0 = meta[1600 + tile];
  const int nvalid = meta[1025 + e] - row0;
  const int tid = threadIdx.x, lane = tid & 63, wave = tid >> 6;

  if (tid < 128) {
    if (tid < nvalid) {
      int pr = perm[row0 + tid];
      rtok[tid] = pr >> 1;
      rwt[tid] = cw[pr];
    } else {
      rtok[tid] = 0;
      rwt[tid] = 0.f;
    }
  }
  __syncthreads();

  const int sr = wave * 8 + (lane >> 3);
  const int kx = ((lane & 7) ^ (lane >> 3)) << 3;
  const bfu* aP[4]; const bfu* bP[4];
#pragma unroll
  for (int j = 0; j < 4; ++j) {
    const int row = j * 32 + sr;
    const int ar = row < nvalid ? row : (nvalid - 1);  // clamp src row only
    aP[j] = h + (size_t)(row0 + ar) * F_ + kx;
    bP[j] = wd + (size_t)e * D_ * F_ + (size_t)(n0 + row) * F_ + kx;
  }

  const int wm = (wave >> 1) * 64, wn = (wave & 1) * 64;
  const int rb = lane & 15, kseg = lane >> 4, x7 = rb & 7;
  int offA[4], offB[4];
#pragma unroll
  for (int i = 0; i < 4; ++i) {
    offA[i] = (wm + i * 16 + rb) * 64 + ((kseg ^ x7) << 3);
    offB[i] = (wn + i * 16 + rb) * 64 + ((kseg ^ x7) << 3);
  }

  floatx4 acc[4][4] = {};

  for (int k0 = 0; k0 < F_; k0 += 64) {
#pragma unroll
    for (int j = 0; j < 4; ++j) {
      const int db = (j * 32 + wave * 8) * 64;
      gload16(aP[j] + k0, As + db);
      gload16(bP[j] + k0, Bs + db);
    }
    __syncthreads();
#pragma unroll
    for (int kh = 0; kh < 2; ++kh) {
      const int kf = kh << 5;
      bf16x8 af[4], bf_[4];
#pragma unroll
      for (int i = 0; i < 4; ++i) {
        af[i] = *(const bf16x8*)&As[offA[i] ^ kf];
        bf_[i] = *(const bf16x8*)&Bs[offB[i] ^ kf];
      }
#pragma unroll
      for (int mi = 0; mi < 4; ++mi)
#pragma unroll
        for (int ni = 0; ni < 4; ++ni)
          acc[mi][ni] = __builtin_amdgcn_mfma_f32_16x16x32_bf16(
              af[mi], bf_[ni], acc[mi][ni], 0, 0, 0);
    }
    __syncthreads();
  }

  const int sq = lane >> 4, sc = lane & 15;
#pragma unroll
  for (int mi = 0; mi < 4; ++mi) {
#pragma unroll
    for (int i = 0; i < 4; ++i) {
      const int r = wm + mi * 16 + sq * 4 + i;
      const float w = rwt[r];
      if (w != 0.f) {
        const int tok = rtok[r];
        float* op = out + (size_t)tok * D_ + n0 + wn + sc;
#pragma unroll
        for (int ni = 0; ni < 4; ++ni)
          atomicAdd(op + ni * 16, w * acc[mi][ni][i]);
      }
    }
  }
}

extern "C" void kernel_launch(void* const* d_in, const int* in_sizes, int n_in,
                              void* d_out, int out_size, void* d_ws, size_t ws_size,
                              hipStream_t stream) {
  const float* x  = (const float*)d_in[0];
  const float* rw = (const float*)d_in[1];
  const float* gw = (const float*)d_in[2];
  const float* uw = (const float*)d_in[3];
  const float* dw = (const float*)d_in[4];
  float* out = (float*)d_out;
  float* logits = out + (size_t)T_ * D_;

  char* ws = (char*)d_ws;
  bfu* xb  = (bfu*)(ws + O_XB);
  bfu* wgt = (bfu*)(ws + O_WG);
  bfu* wut = (bfu*)(ws + O_WU);
  bfu* wdt = (bfu*)(ws + O_WD);
  bfu* hb  = (bfu*)(ws + O_H);
  float* cwp = (float*)(ws + O_CW);
  int* eip  = (int*)(ws + O_EI);
  int* perm = (int*)(ws + O_PM);
  int* meta = (int*)(ws + O_MT);

  hipMemsetAsync(out, 0, (size_t)T_ * D_ * sizeof(float), stream);
  hipMemsetAsync(meta, 0, 4096, stream);

  transpose_cast_kernel<<<dim3(F_ / 64, D_ / 64, E_), 256, 0, stream>>>(gw, wgt, D_, F_);
  transpose_cast_kernel<<<dim3(F_ / 64, D_ / 64, E_), 256, 0, stream>>>(uw, wut, D_, F_);
  transpose_cast_kernel<<<dim3(D_ / 64, F_ / 64, E_), 256, 0, stream>>>(dw, wdt, F_, D_);

  router_kernel<<<T_ / 32, 256, 0, stream>>>(x, rw, xb, logits, cwp, eip, meta);
  scan_kernel<<<1, 64, 0, stream>>>(meta);
  perm_kernel<<<P_ / 256, 256, 0, stream>>>(eip, meta, perm);

  gateup_kernel<<<dim3(F_ / 128, MAXTILES), 256, 0, stream>>>(xb, wgt, wut, hb, perm, meta);
  down_kernel<<<dim3(D_ / 128, MAXTILES), 256, 0, stream>>>(hb, wdt, out, cwp, perm, meta);
}